// Round 3
// baseline (431.820 us; speedup 1.0000x reference)
//
#include <hip/hip_runtime.h>

#define B_ 16
#define S_ 4096
#define D_ 64
#define H_ 8
#define NB_ 64          // n_buckets
#define M_ 64           // bucket_size
#define CHUNKS_ 512     // per batch = H_*NB_
#define LOG2E 1.4426950408889634f
#define LN2 0.6931471805599453f

#define QS_ 72          // Q/K LDS row stride (shorts)
#define VS_ 136         // V^T / P LDS row stride (shorts)

typedef short short8 __attribute__((ext_vector_type(8)));
typedef float floatx4 __attribute__((ext_vector_type(4)));

__device__ __forceinline__ unsigned short f2bf(float x) {
    unsigned int u = __float_as_uint(x);
    unsigned int r = (u + 0x7FFFu + ((u >> 16) & 1u)) >> 16;
    return (unsigned short)r;
}
__device__ __forceinline__ float bf2f(unsigned short s) {
    return __uint_as_float(((unsigned int)s) << 16);
}
__device__ __forceinline__ unsigned pk(float a, float b) {
    return (unsigned)f2bf(a) | ((unsigned)f2bf(b) << 16);
}
__device__ __forceinline__ uint4 pack8(float4 a, float4 b) {
    uint4 u;
    u.x = pk(a.x, a.y); u.y = pk(a.z, a.w);
    u.z = pk(b.x, b.y); u.w = pk(b.z, b.w);
    return u;
}

// ---------------- K1: hashing ----------------
// 4 tokens per thread: same rot LDS reads serve 4 tokens (DS pipe was the
// bottleneck: 512 broadcast b128/wave). Per-token FP expression order is
// IDENTICAL to the round-1/2 kernel -> identical bucket decisions.
__global__ void __launch_bounds__(256, 2)
hash_kernel(const float* __restrict__ qk,
            const float* __restrict__ rot,
            int* __restrict__ bucket) {
    int bh = blockIdx.x >> 2;      // (b*H + h)
    int tc = blockIdx.x & 3;       // 1024-token chunk
    int h = bh & 7;
    int b = bh >> 3;

    __shared__ float rl[64 * 32];
    #pragma unroll
    for (int k = 0; k < 8; k++) {
        int e = k * 256 + threadIdx.x;
        rl[e] = rot[(e >> 5) * (H_ * 32) + h * 32 + (e & 31)];
    }
    __syncthreads();

    const int t0 = tc * 1024 + threadIdx.x;   // tokens t0 + 256*u, u=0..3

    float acc[4][32];
    #pragma unroll
    for (int u = 0; u < 4; u++)
        #pragma unroll
        for (int i = 0; i < 32; i++) acc[u][i] = 0.f;

    #pragma unroll 2
    for (int k = 0; k < 16; k++) {
        float4 x[4];
        #pragma unroll
        for (int u = 0; u < 4; u++)
            x[u] = ((const float4*)(qk + ((size_t)(b * S_ + t0 + 256 * u)) * D_))[k];
        const float* r0 = &rl[(4 * k + 0) * 32];
        const float* r1 = &rl[(4 * k + 1) * 32];
        const float* r2 = &rl[(4 * k + 2) * 32];
        const float* r3 = &rl[(4 * k + 3) * 32];
        #pragma unroll
        for (int i = 0; i < 32; i++) {
            float a0 = r0[i], a1 = r1[i], a2 = r2[i], a3 = r3[i];
            #pragma unroll
            for (int u = 0; u < 4; u++)
                acc[u][i] += x[u].x * a0 + x[u].y * a1 + x[u].z * a2 + x[u].w * a3;
        }
    }

    #pragma unroll
    for (int u = 0; u < 4; u++) {
        float best = acc[u][0];
        int bi = 0;
        #pragma unroll
        for (int i = 1; i < 32; i++)
            if (acc[u][i] > best) { best = acc[u][i]; bi = i; }
        #pragma unroll
        for (int i = 0; i < 32; i++) {
            float nv = -acc[u][i];
            if (nv > best) { best = nv; bi = 32 + i; }
        }
        bucket[bh * S_ + t0 + 256 * u] = bi;
    }
}

// ---------------- K2: per-(b,h) stable counting sort ----------------
__global__ void sort_kernel(const int* __restrict__ bucket,
                            int* __restrict__ st) {
    int bh = blockIdx.x;
    int lane = threadIdx.x;
    __shared__ int bl[S_];
    __shared__ int cnt[64 * 64];
    __shared__ int tot[64];
    __shared__ int start[64];

    const int base = bh * S_;
    for (int k = 0; k < 64; k++) bl[k * 64 + lane] = bucket[base + k * 64 + lane];
    for (int k = 0; k < 64; k++) cnt[k * 64 + lane] = 0;
    __syncthreads();

    {
        int g = lane;
        for (int j = 0; j < 64; j++) cnt[g * 64 + bl[g * 64 + j]]++;
    }
    __syncthreads();
    {
        int bk = lane, s = 0;
        for (int g = 0; g < 64; g++) s += cnt[g * 64 + bk];
        tot[bk] = s;
    }
    __syncthreads();
    if (lane == 0) {
        int run = 0;
        for (int bk = 0; bk < 64; bk++) { start[bk] = run; run += tot[bk]; }
    }
    __syncthreads();
    {
        int bk = lane;
        int run = start[bk];
        for (int g = 0; g < 64; g++) {
            int c = cnt[g * 64 + bk];
            cnt[g * 64 + bk] = run;
            run += c;
        }
    }
    __syncthreads();
    {
        int g = lane;
        for (int j = 0; j < 64; j++) {
            int t = g * 64 + j;
            int bk = bl[t];
            int p = cnt[g * 64 + bk]++;
            st[base + p] = t;
        }
    }
}

// ---------------- K3: MFMA chunked attention ----------------
// Block = 1 chunk (64 q x 128 kv), 4 waves. V^T is staged AFTER QK^T into
// the Ks region (union) -> 45.8 KB LDS -> 3 blocks/CU. V^T columns are
// XOR-32 swizzled by (row>>4)&1 to kill the 4-way write bank conflict.
template <typename OT>
__global__ void __launch_bounds__(256, 3)
attn_kernel(const float* __restrict__ qk,
            const float* __restrict__ v,
            const int* __restrict__ st,
            OT* __restrict__ ou,               // (B,H,S,D)
            float* __restrict__ lse_u) {       // (B,H,S)
    const int tid = threadIdx.x;
    const int b = blockIdx.x >> 9;
    const int cc = blockIdx.x & 511;
    const int prev = (cc - 1) & 511;
    const int h = cc >> 6;

    __shared__ unsigned short KV[128 * QS_];   // Ks rows, then V^T (aliased)
    __shared__ unsigned short Qs[64 * QS_];    // Q rows (raw), bf16
    __shared__ unsigned short Ps[64 * VS_];    // P (then O) per-wave
    __shared__ int tkv[128];
    __shared__ float bounds[64];

    const int stBase = b * (CHUNKS_ * M_);
    if (tid < 128) tkv[tid] = st[stBase + (tid < 64 ? cc : prev) * 64 + (tid & 63)];
    __syncthreads();

    const int stok = tid >> 2;                 // 0..63 (token within pass)
    const int q4 = tid & 3;                    // 16-feature slice

    // ---- stage K/Q; hold V (packed bf16) in regs ----
    unsigned vpk[2][8];
    #pragma unroll
    for (int p = 0; p < 2; p++) {
        int tok = p * 64 + stok;
        int pos = tkv[tok];
        const float4* src = (const float4*)(qk + (size_t)(b * S_ + pos) * 64) + q4 * 4;
        float4 x0 = src[0], x1 = src[1], x2 = src[2], x3 = src[3];
        const float4* vsrc = (const float4*)(v + (size_t)(b * S_ + pos) * 64) + q4 * 4;
        float4 y0 = vsrc[0], y1 = vsrc[1], y2 = vsrc[2], y3 = vsrc[3];

        float ss = x0.x*x0.x + x0.y*x0.y + x0.z*x0.z + x0.w*x0.w
                 + x1.x*x1.x + x1.y*x1.y + x1.z*x1.z + x1.w*x1.w
                 + x2.x*x2.x + x2.y*x2.y + x2.z*x2.z + x2.w*x2.w
                 + x3.x*x3.x + x3.y*x3.y + x3.z*x3.z + x3.w*x3.w;
        ss += __shfl_xor(ss, 1);
        ss += __shfl_xor(ss, 2);
        float nrm = sqrtf(ss);
        float rn = 1.f / fmaxf(nrm, 1e-12f);

        float4 k0 = make_float4(x0.x*rn, x0.y*rn, x0.z*rn, x0.w*rn);
        float4 k1 = make_float4(x1.x*rn, x1.y*rn, x1.z*rn, x1.w*rn);
        float4 k2 = make_float4(x2.x*rn, x2.y*rn, x2.z*rn, x2.w*rn);
        float4 k3 = make_float4(x3.x*rn, x3.y*rn, x3.z*rn, x3.w*rn);
        *(uint4*)&KV[tok * QS_ + q4 * 16]     = pack8(k0, k1);
        *(uint4*)&KV[tok * QS_ + q4 * 16 + 8] = pack8(k2, k3);

        vpk[p][0] = pk(y0.x, y0.y); vpk[p][1] = pk(y0.z, y0.w);
        vpk[p][2] = pk(y1.x, y1.y); vpk[p][3] = pk(y1.z, y1.w);
        vpk[p][4] = pk(y2.x, y2.y); vpk[p][5] = pk(y2.z, y2.w);
        vpk[p][6] = pk(y3.x, y3.y); vpk[p][7] = pk(y3.z, y3.w);

        if (p == 0) {
            *(uint4*)&Qs[tok * QS_ + q4 * 16]     = pack8(x0, x1);
            *(uint4*)&Qs[tok * QS_ + q4 * 16 + 8] = pack8(x2, x3);
            if (q4 == 0) bounds[tok] = nrm * 0.125f;
        }
    }
    __syncthreads();

    const int lane = tid & 63;
    const int w = tid >> 6;
    const int lm = lane & 15;
    const int lq = lane >> 4;

    // ---- QK^T ----
    const short8 a0 = *(const short8*)&Qs[(w * 16 + lm) * QS_ + lq * 8];
    const short8 a1 = *(const short8*)&Qs[(w * 16 + lm) * QS_ + 32 + lq * 8];
    floatx4 C[8];
    #pragma unroll
    for (int nt = 0; nt < 8; nt++) {
        const short8 b0 = *(const short8*)&KV[(nt * 16 + lm) * QS_ + lq * 8];
        const short8 b1 = *(const short8*)&KV[(nt * 16 + lm) * QS_ + 32 + lq * 8];
        floatx4 c = {0.f, 0.f, 0.f, 0.f};
        c = __builtin_amdgcn_mfma_f32_16x16x32_bf16(a0, b0, c, 0, 0, 0);
        c = __builtin_amdgcn_mfma_f32_16x16x32_bf16(a1, b1, c, 0, 0, 0);
        C[nt] = c;
    }

    // ---- mask + exp(bound trick) + P->LDS (A-layout) ----
    int tqr[4]; float bndr[4];
    #pragma unroll
    for (int r = 0; r < 4; r++) {
        int row = w * 16 + lq * 4 + r;
        tqr[r] = tkv[row];
        bndr[r] = bounds[row];
    }
    float lsum[4] = {0.f, 0.f, 0.f, 0.f};
    float nself[4] = {0.f, 0.f, 0.f, 0.f};
    #pragma unroll
    for (int nt = 0; nt < 8; nt++) {
        int tkc = tkv[nt * 16 + lm];
        #pragma unroll
        for (int r = 0; r < 4; r++) {
            float d = C[nt][r] * 0.125f;
            nself[r] += (tkc == tqr[r]) ? 1.f : 0.f;
            float pp = (tkc < tqr[r]) ? exp2f((d - bndr[r]) * LOG2E) : 0.f;
            lsum[r] += pp;
            Ps[(w * 16 + lq * 4 + r) * VS_ + nt * 16 + lm] = f2bf(pp);
        }
    }
    #pragma unroll
    for (int r = 0; r < 4; r++) {
        #pragma unroll
        for (int s = 1; s < 16; s <<= 1) {
            lsum[r]  += __shfl_xor(lsum[r], s);
            nself[r] += __shfl_xor(nself[r], s);
        }
    }
    __syncthreads();   // all waves done reading Ks

    // ---- restage V^T over Ks region (swizzled columns) ----
    {
        const int sw = (q4 & 1) << 5;
        #pragma unroll
        for (int p = 0; p < 2; p++) {
            int col = (p * 64 + stok) ^ sw;
            #pragma unroll
            for (int i = 0; i < 16; i++) {
                unsigned u = vpk[p][i >> 1];
                unsigned short hv = (i & 1) ? (unsigned short)(u >> 16)
                                            : (unsigned short)(u & 0xFFFFu);
                KV[(q4 * 16 + i) * VS_ + col] = hv;
            }
        }
    }
    __syncthreads();

    // ---- PV ----
    floatx4 O[4];
    #pragma unroll
    for (int nt2 = 0; nt2 < 4; nt2++) O[nt2] = floatx4{0.f, 0.f, 0.f, 0.f};
    #pragma unroll
    for (int kt = 0; kt < 4; kt++) {
        const short8 pa = *(const short8*)&Ps[(w * 16 + lm) * VS_ + kt * 32 + lq * 8];
        #pragma unroll
        for (int nt2 = 0; nt2 < 4; nt2++) {
            const short8 vb = *(const short8*)&KV[(nt2 * 16 + lm) * VS_
                                + ((kt ^ (nt2 & 1)) * 32) + lq * 8];
            O[nt2] = __builtin_amdgcn_mfma_f32_16x16x32_bf16(pa, vb, O[nt2], 0, 0, 0);
        }
    }

    // ---- epilogue ----
    const size_t oBaseBH = (size_t)(b * H_ + h) * S_;
    #pragma unroll
    for (int r = 0; r < 4; r++) {
        int pos = tqr[r];
        float invl, lse;
        if (lsum[r] > 0.f) {
            invl = 1.f / lsum[r];
            lse = bndr[r] + log2f(lsum[r]) * LN2;
        } else {
            invl = 1.f;
            lse = -50000.f + logf(nself[r]);
            #pragma unroll
            for (int nt2 = 0; nt2 < 4; nt2++)
                O[nt2][r] = v[(size_t)(b * S_ + pos) * 64 + nt2 * 16 + lm];
        }
        if constexpr (sizeof(OT) == 4) {
            float* dst = (float*)ou + (oBaseBH + pos) * 64 + lm;
            #pragma unroll
            for (int nt2 = 0; nt2 < 4; nt2++)
                dst[nt2 * 16] = O[nt2][r] * invl;
        } else {
            #pragma unroll
            for (int nt2 = 0; nt2 < 4; nt2++)
                Ps[(w * 16 + lq * 4 + r) * VS_ + nt2 * 16 + lm] = f2bf(O[nt2][r] * invl);
        }
        if (lm == 0) lse_u[oBaseBH + pos] = lse;
    }
    if constexpr (sizeof(OT) == 2) {
        int rrow = lane >> 2;
        int seg = lane & 3;
        int qrow = w * 16 + rrow;
        int pos = tkv[qrow];
        uint4 u0 = *(uint4*)&Ps[qrow * VS_ + seg * 16];
        uint4 u1 = *(uint4*)&Ps[qrow * VS_ + seg * 16 + 8];
        unsigned short* dst = (unsigned short*)ou + (oBaseBH + pos) * 64 + seg * 16;
        *(uint4*)dst = u0;
        *(uint4*)(dst + 8) = u1;
    }
}

// ---------------- K4: combine hash rounds ----------------
template <typename OT>
__global__ void combine_kernel(const OT* __restrict__ ou,
                               const float* __restrict__ lse_u,
                               float* __restrict__ out) {
    int idx = blockIdx.x * 256 + threadIdx.x;
    int f = idx & 63;
    int t = (idx >> 6) & (S_ - 1);
    int b = idx >> 18;

    const float* lp = lse_u + (size_t)b * (H_ * S_) + t;
    float le[H_];
    float m = -3.4e38f;
    #pragma unroll
    for (int h = 0; h < H_; h++) {
        le[h] = lp[h * S_];
        m = fmaxf(m, le[h]);
    }
    float s = 0.f, e[H_];
    #pragma unroll
    for (int h = 0; h < H_; h++) {
        e[h] = exp2f((le[h] - m) * LOG2E);
        s += e[h];
    }
    float o = 0.f;
    #pragma unroll
    for (int h = 0; h < H_; h++) {
        OT u = ou[(size_t)((b * H_ + h) * S_ + t) * D_ + f];
        if constexpr (sizeof(OT) == 2) o += e[h] * bf2f((unsigned short)u);
        else                           o += e[h] * (float)u;
    }
    out[idx] = o / s;
}

extern "C" void kernel_launch(void* const* d_in, const int* in_sizes, int n_in,
                              void* d_out, int out_size, void* d_ws, size_t ws_size,
                              hipStream_t stream) {
    const float* qk  = (const float*)d_in[0];
    const float* v   = (const float*)d_in[1];
    const float* rot = (const float*)d_in[2];
    float* out = (float*)d_out;

    char* ws = (char*)d_ws;
    int* bucket  = (int*)(ws);
    int* st      = (int*)(ws + 2097152);
    float* lse_u = (float*)(ws + 4194304);
    void* ou     = (void*)(ws + 6291456);

    const size_t ou_fp32_need = 6291456 + (size_t)B_ * H_ * S_ * D_ * sizeof(float);
    const bool fp32_ou = (ws_size >= ou_fp32_need);

    hash_kernel<<<dim3(B_ * H_ * (S_ / 1024)), dim3(256), 0, stream>>>(qk, rot, bucket);
    sort_kernel<<<dim3(B_ * H_), dim3(64), 0, stream>>>(bucket, st);
    if (fp32_ou) {
        attn_kernel<float><<<dim3(B_ * CHUNKS_), dim3(256), 0, stream>>>(
            qk, v, st, (float*)ou, lse_u);
        combine_kernel<float><<<dim3((B_ * S_ * D_) / 256), dim3(256), 0, stream>>>(
            (const float*)ou, lse_u, out);
    } else {
        attn_kernel<unsigned short><<<dim3(B_ * CHUNKS_), dim3(256), 0, stream>>>(
            qk, v, st, (unsigned short*)ou, lse_u);
        combine_kernel<unsigned short><<<dim3((B_ * S_ * D_) / 256), dim3(256), 0, stream>>>(
            (const unsigned short*)ou, lse_u, out);
    }
}

// Round 4
// 245.197 us; speedup vs baseline: 1.7611x; 1.7611x over previous
//
#include <hip/hip_runtime.h>

#define B_ 16
#define S_ 4096
#define D_ 64
#define H_ 8
#define NB_ 64          // n_buckets
#define M_ 64           // bucket_size
#define CHUNKS_ 512     // per batch = H_*NB_
#define LOG2E 1.4426950408889634f
#define LN2 0.6931471805599453f

#define QS_ 72          // Q/K LDS row stride (shorts)
#define VS_ 136         // V^T / P LDS row stride (shorts)

typedef short short8 __attribute__((ext_vector_type(8)));
typedef float floatx4 __attribute__((ext_vector_type(4)));

__device__ __forceinline__ unsigned short f2bf(float x) {
    unsigned int u = __float_as_uint(x);
    unsigned int r = (u + 0x7FFFu + ((u >> 16) & 1u)) >> 16;
    return (unsigned short)r;
}
__device__ __forceinline__ float bf2f(unsigned short s) {
    return __uint_as_float(((unsigned int)s) << 16);
}
__device__ __forceinline__ unsigned pk(float a, float b) {
    return (unsigned)f2bf(a) | ((unsigned)f2bf(b) << 16);
}
__device__ __forceinline__ uint4 pack8(float4 a, float4 b) {
    uint4 u;
    u.x = pk(a.x, a.y); u.y = pk(a.z, a.w);
    u.z = pk(b.x, b.y); u.w = pk(b.z, b.w);
    return u;
}

// ---------------- K1: hashing ----------------
// 2 tokens/thread: acc[2][32]=64 VGPRs (round-3's acc[4][32]=128 spilled to
// scratch: 613 MB WRITE_SIZE). Per-token FP expression order is IDENTICAL
// to round-1/2 -> identical bucket decisions.
__global__ void __launch_bounds__(256)
hash_kernel(const float* __restrict__ qk,
            const float* __restrict__ rot,
            int* __restrict__ bucket) {
    int bh = blockIdx.x >> 3;      // (b*H + h)
    int tc = blockIdx.x & 7;       // 512-token chunk
    int h = bh & 7;
    int b = bh >> 3;

    __shared__ float rl[64 * 32];
    #pragma unroll
    for (int k = 0; k < 8; k++) {
        int e = k * 256 + threadIdx.x;
        rl[e] = rot[(e >> 5) * (H_ * 32) + h * 32 + (e & 31)];
    }
    __syncthreads();

    const int t0 = tc * 512 + threadIdx.x;   // tokens t0, t0+256

    const float4* qrow0 = (const float4*)(qk + ((size_t)(b * S_ + t0)) * D_);
    const float4* qrow1 = (const float4*)(qk + ((size_t)(b * S_ + t0 + 256)) * D_);

    float acc[2][32];
    #pragma unroll
    for (int u = 0; u < 2; u++)
        #pragma unroll
        for (int i = 0; i < 32; i++) acc[u][i] = 0.f;

    for (int k = 0; k < 16; k++) {
        float4 x0 = qrow0[k];
        float4 x1 = qrow1[k];
        const float* r0 = &rl[(4 * k + 0) * 32];
        const float* r1 = &rl[(4 * k + 1) * 32];
        const float* r2 = &rl[(4 * k + 2) * 32];
        const float* r3 = &rl[(4 * k + 3) * 32];
        #pragma unroll
        for (int i = 0; i < 32; i++) {
            float a0 = r0[i], a1 = r1[i], a2 = r2[i], a3 = r3[i];
            acc[0][i] += x0.x * a0 + x0.y * a1 + x0.z * a2 + x0.w * a3;
            acc[1][i] += x1.x * a0 + x1.y * a1 + x1.z * a2 + x1.w * a3;
        }
    }

    #pragma unroll
    for (int u = 0; u < 2; u++) {
        float best = acc[u][0];
        int bi = 0;
        #pragma unroll
        for (int i = 1; i < 32; i++)
            if (acc[u][i] > best) { best = acc[u][i]; bi = i; }
        #pragma unroll
        for (int i = 0; i < 32; i++) {
            float nv = -acc[u][i];
            if (nv > best) { best = nv; bi = 32 + i; }
        }
        bucket[bh * S_ + t0 + 256 * u] = bi;
    }
}

// ---------------- K2: per-(b,h) stable counting sort ----------------
__global__ void sort_kernel(const int* __restrict__ bucket,
                            int* __restrict__ st) {
    int bh = blockIdx.x;
    int lane = threadIdx.x;
    __shared__ int bl[S_];
    __shared__ int cnt[64 * 64];
    __shared__ int tot[64];
    __shared__ int start[64];

    const int base = bh * S_;
    for (int k = 0; k < 64; k++) bl[k * 64 + lane] = bucket[base + k * 64 + lane];
    for (int k = 0; k < 64; k++) cnt[k * 64 + lane] = 0;
    __syncthreads();

    {
        int g = lane;
        for (int j = 0; j < 64; j++) cnt[g * 64 + bl[g * 64 + j]]++;
    }
    __syncthreads();
    {
        int bk = lane, s = 0;
        for (int g = 0; g < 64; g++) s += cnt[g * 64 + bk];
        tot[bk] = s;
    }
    __syncthreads();
    if (lane == 0) {
        int run = 0;
        for (int bk = 0; bk < 64; bk++) { start[bk] = run; run += tot[bk]; }
    }
    __syncthreads();
    {
        int bk = lane;
        int run = start[bk];
        for (int g = 0; g < 64; g++) {
            int c = cnt[g * 64 + bk];
            cnt[g * 64 + bk] = run;
            run += c;
        }
    }
    __syncthreads();
    {
        int g = lane;
        for (int j = 0; j < 64; j++) {
            int t = g * 64 + j;
            int bk = bl[t];
            int p = cnt[g * 64 + bk]++;
            st[base + p] = t;
        }
    }
}

// ---------------- K3: MFMA chunked attention ----------------
// Block = 1 chunk (64 q x 128 kv), 4 waves. V^T is staged AFTER QK^T into
// the Ks region (union) -> 45.8 KB LDS -> 3 blocks/CU. V^T columns are
// XOR-32 swizzled by (row>>4)&1 to kill the 4-way write bank conflict.
template <typename OT>
__global__ void __launch_bounds__(256, 3)
attn_kernel(const float* __restrict__ qk,
            const float* __restrict__ v,
            const int* __restrict__ st,
            OT* __restrict__ ou,               // (B,H,S,D)
            float* __restrict__ lse_u) {       // (B,H,S)
    const int tid = threadIdx.x;
    const int b = blockIdx.x >> 9;
    const int cc = blockIdx.x & 511;
    const int prev = (cc - 1) & 511;
    const int h = cc >> 6;

    __shared__ unsigned short KV[128 * QS_];   // Ks rows, then V^T (aliased)
    __shared__ unsigned short Qs[64 * QS_];    // Q rows (raw), bf16
    __shared__ unsigned short Ps[64 * VS_];    // P (then O) per-wave
    __shared__ int tkv[128];
    __shared__ float bounds[64];

    const int stBase = b * (CHUNKS_ * M_);
    if (tid < 128) tkv[tid] = st[stBase + (tid < 64 ? cc : prev) * 64 + (tid & 63)];
    __syncthreads();

    const int stok = tid >> 2;                 // 0..63 (token within pass)
    const int q4 = tid & 3;                    // 16-feature slice

    // ---- stage K/Q; hold V (packed bf16) in regs ----
    unsigned vpk[2][8];
    #pragma unroll
    for (int p = 0; p < 2; p++) {
        int tok = p * 64 + stok;
        int pos = tkv[tok];
        const float4* src = (const float4*)(qk + (size_t)(b * S_ + pos) * 64) + q4 * 4;
        float4 x0 = src[0], x1 = src[1], x2 = src[2], x3 = src[3];
        const float4* vsrc = (const float4*)(v + (size_t)(b * S_ + pos) * 64) + q4 * 4;
        float4 y0 = vsrc[0], y1 = vsrc[1], y2 = vsrc[2], y3 = vsrc[3];

        float ss = x0.x*x0.x + x0.y*x0.y + x0.z*x0.z + x0.w*x0.w
                 + x1.x*x1.x + x1.y*x1.y + x1.z*x1.z + x1.w*x1.w
                 + x2.x*x2.x + x2.y*x2.y + x2.z*x2.z + x2.w*x2.w
                 + x3.x*x3.x + x3.y*x3.y + x3.z*x3.z + x3.w*x3.w;
        ss += __shfl_xor(ss, 1);
        ss += __shfl_xor(ss, 2);
        float nrm = sqrtf(ss);
        float rn = 1.f / fmaxf(nrm, 1e-12f);

        float4 k0 = make_float4(x0.x*rn, x0.y*rn, x0.z*rn, x0.w*rn);
        float4 k1 = make_float4(x1.x*rn, x1.y*rn, x1.z*rn, x1.w*rn);
        float4 k2 = make_float4(x2.x*rn, x2.y*rn, x2.z*rn, x2.w*rn);
        float4 k3 = make_float4(x3.x*rn, x3.y*rn, x3.z*rn, x3.w*rn);
        *(uint4*)&KV[tok * QS_ + q4 * 16]     = pack8(k0, k1);
        *(uint4*)&KV[tok * QS_ + q4 * 16 + 8] = pack8(k2, k3);

        vpk[p][0] = pk(y0.x, y0.y); vpk[p][1] = pk(y0.z, y0.w);
        vpk[p][2] = pk(y1.x, y1.y); vpk[p][3] = pk(y1.z, y1.w);
        vpk[p][4] = pk(y2.x, y2.y); vpk[p][5] = pk(y2.z, y2.w);
        vpk[p][6] = pk(y3.x, y3.y); vpk[p][7] = pk(y3.z, y3.w);

        if (p == 0) {
            *(uint4*)&Qs[tok * QS_ + q4 * 16]     = pack8(x0, x1);
            *(uint4*)&Qs[tok * QS_ + q4 * 16 + 8] = pack8(x2, x3);
            if (q4 == 0) bounds[tok] = nrm * 0.125f;
        }
    }
    __syncthreads();

    const int lane = tid & 63;
    const int w = tid >> 6;
    const int lm = lane & 15;
    const int lq = lane >> 4;

    // ---- QK^T ----
    const short8 a0 = *(const short8*)&Qs[(w * 16 + lm) * QS_ + lq * 8];
    const short8 a1 = *(const short8*)&Qs[(w * 16 + lm) * QS_ + 32 + lq * 8];
    floatx4 C[8];
    #pragma unroll
    for (int nt = 0; nt < 8; nt++) {
        const short8 b0 = *(const short8*)&KV[(nt * 16 + lm) * QS_ + lq * 8];
        const short8 b1 = *(const short8*)&KV[(nt * 16 + lm) * QS_ + 32 + lq * 8];
        floatx4 c = {0.f, 0.f, 0.f, 0.f};
        c = __builtin_amdgcn_mfma_f32_16x16x32_bf16(a0, b0, c, 0, 0, 0);
        c = __builtin_amdgcn_mfma_f32_16x16x32_bf16(a1, b1, c, 0, 0, 0);
        C[nt] = c;
    }

    // ---- mask + exp(bound trick) + P->LDS (A-layout) ----
    int tqr[4]; float bndr[4];
    #pragma unroll
    for (int r = 0; r < 4; r++) {
        int row = w * 16 + lq * 4 + r;
        tqr[r] = tkv[row];
        bndr[r] = bounds[row];
    }
    float lsum[4] = {0.f, 0.f, 0.f, 0.f};
    float nself[4] = {0.f, 0.f, 0.f, 0.f};
    #pragma unroll
    for (int nt = 0; nt < 8; nt++) {
        int tkc = tkv[nt * 16 + lm];
        #pragma unroll
        for (int r = 0; r < 4; r++) {
            float d = C[nt][r] * 0.125f;
            nself[r] += (tkc == tqr[r]) ? 1.f : 0.f;
            float pp = (tkc < tqr[r]) ? exp2f((d - bndr[r]) * LOG2E) : 0.f;
            lsum[r] += pp;
            Ps[(w * 16 + lq * 4 + r) * VS_ + nt * 16 + lm] = f2bf(pp);
        }
    }
    #pragma unroll
    for (int r = 0; r < 4; r++) {
        #pragma unroll
        for (int s = 1; s < 16; s <<= 1) {
            lsum[r]  += __shfl_xor(lsum[r], s);
            nself[r] += __shfl_xor(nself[r], s);
        }
    }
    __syncthreads();   // all waves done reading Ks

    // ---- restage V^T over Ks region (swizzled columns) ----
    {
        const int sw = (q4 & 1) << 5;
        #pragma unroll
        for (int p = 0; p < 2; p++) {
            int col = (p * 64 + stok) ^ sw;
            #pragma unroll
            for (int i = 0; i < 16; i++) {
                unsigned u = vpk[p][i >> 1];
                unsigned short hv = (i & 1) ? (unsigned short)(u >> 16)
                                            : (unsigned short)(u & 0xFFFFu);
                KV[(q4 * 16 + i) * VS_ + col] = hv;
            }
        }
    }
    __syncthreads();

    // ---- PV ----
    floatx4 O[4];
    #pragma unroll
    for (int nt2 = 0; nt2 < 4; nt2++) O[nt2] = floatx4{0.f, 0.f, 0.f, 0.f};
    #pragma unroll
    for (int kt = 0; kt < 4; kt++) {
        const short8 pa = *(const short8*)&Ps[(w * 16 + lm) * VS_ + kt * 32 + lq * 8];
        #pragma unroll
        for (int nt2 = 0; nt2 < 4; nt2++) {
            const short8 vb = *(const short8*)&KV[(nt2 * 16 + lm) * VS_
                                + ((kt ^ (nt2 & 1)) * 32) + lq * 8];
            O[nt2] = __builtin_amdgcn_mfma_f32_16x16x32_bf16(pa, vb, O[nt2], 0, 0, 0);
        }
    }

    // ---- epilogue ----
    const size_t oBaseBH = (size_t)(b * H_ + h) * S_;
    #pragma unroll
    for (int r = 0; r < 4; r++) {
        int pos = tqr[r];
        float invl, lse;
        if (lsum[r] > 0.f) {
            invl = 1.f / lsum[r];
            lse = bndr[r] + log2f(lsum[r]) * LN2;
        } else {
            invl = 1.f;
            lse = -50000.f + logf(nself[r]);
            #pragma unroll
            for (int nt2 = 0; nt2 < 4; nt2++)
                O[nt2][r] = v[(size_t)(b * S_ + pos) * 64 + nt2 * 16 + lm];
        }
        if constexpr (sizeof(OT) == 4) {
            float* dst = (float*)ou + (oBaseBH + pos) * 64 + lm;
            #pragma unroll
            for (int nt2 = 0; nt2 < 4; nt2++)
                dst[nt2 * 16] = O[nt2][r] * invl;
        } else {
            #pragma unroll
            for (int nt2 = 0; nt2 < 4; nt2++)
                Ps[(w * 16 + lq * 4 + r) * VS_ + nt2 * 16 + lm] = f2bf(O[nt2][r] * invl);
        }
        if (lm == 0) lse_u[oBaseBH + pos] = lse;
    }
    if constexpr (sizeof(OT) == 2) {
        int rrow = lane >> 2;
        int seg = lane & 3;
        int qrow = w * 16 + rrow;
        int pos = tkv[qrow];
        uint4 u0 = *(uint4*)&Ps[qrow * VS_ + seg * 16];
        uint4 u1 = *(uint4*)&Ps[qrow * VS_ + seg * 16 + 8];
        unsigned short* dst = (unsigned short*)ou + (oBaseBH + pos) * 64 + seg * 16;
        *(uint4*)dst = u0;
        *(uint4*)(dst + 8) = u1;
    }
}

// ---------------- K4: combine hash rounds ----------------
template <typename OT>
__global__ void combine_kernel(const OT* __restrict__ ou,
                               const float* __restrict__ lse_u,
                               float* __restrict__ out) {
    int idx = blockIdx.x * 256 + threadIdx.x;
    int f = idx & 63;
    int t = (idx >> 6) & (S_ - 1);
    int b = idx >> 18;

    const float* lp = lse_u + (size_t)b * (H_ * S_) + t;
    float le[H_];
    float m = -3.4e38f;
    #pragma unroll
    for (int h = 0; h < H_; h++) {
        le[h] = lp[h * S_];
        m = fmaxf(m, le[h]);
    }
    float s = 0.f, e[H_];
    #pragma unroll
    for (int h = 0; h < H_; h++) {
        e[h] = exp2f((le[h] - m) * LOG2E);
        s += e[h];
    }
    float o = 0.f;
    #pragma unroll
    for (int h = 0; h < H_; h++) {
        OT u = ou[(size_t)((b * H_ + h) * S_ + t) * D_ + f];
        if constexpr (sizeof(OT) == 2) o += e[h] * bf2f((unsigned short)u);
        else                           o += e[h] * (float)u;
    }
    out[idx] = o / s;
}

extern "C" void kernel_launch(void* const* d_in, const int* in_sizes, int n_in,
                              void* d_out, int out_size, void* d_ws, size_t ws_size,
                              hipStream_t stream) {
    const float* qk  = (const float*)d_in[0];
    const float* v   = (const float*)d_in[1];
    const float* rot = (const float*)d_in[2];
    float* out = (float*)d_out;

    char* ws = (char*)d_ws;
    int* bucket  = (int*)(ws);
    int* st      = (int*)(ws + 2097152);
    float* lse_u = (float*)(ws + 4194304);
    void* ou     = (void*)(ws + 6291456);

    const size_t ou_fp32_need = 6291456 + (size_t)B_ * H_ * S_ * D_ * sizeof(float);
    const bool fp32_ou = (ws_size >= ou_fp32_need);

    hash_kernel<<<dim3(B_ * H_ * (S_ / 512)), dim3(256), 0, stream>>>(qk, rot, bucket);
    sort_kernel<<<dim3(B_ * H_), dim3(64), 0, stream>>>(bucket, st);
    if (fp32_ou) {
        attn_kernel<float><<<dim3(B_ * CHUNKS_), dim3(256), 0, stream>>>(
            qk, v, st, (float*)ou, lse_u);
        combine_kernel<float><<<dim3((B_ * S_ * D_) / 256), dim3(256), 0, stream>>>(
            (const float*)ou, lse_u, out);
    } else {
        attn_kernel<unsigned short><<<dim3(B_ * CHUNKS_), dim3(256), 0, stream>>>(
            qk, v, st, (unsigned short*)ou, lse_u);
        combine_kernel<unsigned short><<<dim3((B_ * S_ * D_) / 256), dim3(256), 0, stream>>>(
            (const unsigned short*)ou, lse_u, out);
    }
}

// Round 5
// 225.064 us; speedup vs baseline: 1.9187x; 1.0895x over previous
//
#include <hip/hip_runtime.h>
#include <hip/hip_bf16.h>

#define B_ 16
#define S_ 4096
#define D_ 64
#define H_ 8
#define NB_ 64          // n_buckets
#define M_ 64           // bucket_size
#define CHUNKS_ 512     // per batch = H_*NB_
#define LOG2E 1.4426950408889634f
#define LN2 0.6931471805599453f

#define QS_ 72          // K LDS row stride (shorts)
#define VS_ 136         // Ps row stride (shorts)
#define VTS_ 68         // V^T row stride (dwords)

typedef short short8 __attribute__((ext_vector_type(8)));
typedef float floatx4 __attribute__((ext_vector_type(4)));

__device__ __forceinline__ unsigned short f2bf(float x) {
    unsigned int u = __float_as_uint(x);
    unsigned int r = (u + 0x7FFFu + ((u >> 16) & 1u)) >> 16;
    return (unsigned short)r;
}
__device__ __forceinline__ float bf2f(unsigned short s) {
    return __uint_as_float(((unsigned int)s) << 16);
}
__device__ __forceinline__ unsigned pk2(float a, float b) {
    __hip_bfloat162 h = __float22bfloat162_rn(make_float2(a, b));
    return *(unsigned*)&h;
}
__device__ __forceinline__ uint4 pack8(float4 a, float4 b) {
    uint4 u;
    u.x = pk2(a.x, a.y); u.y = pk2(a.z, a.w);
    u.z = pk2(b.x, b.y); u.w = pk2(b.z, b.w);
    return u;
}

// ---------------- K1: hashing ----------------
// 2 tokens/thread. Per-token FP expression order IDENTICAL to rounds 1-4
// (frozen: bucket decisions must not change).
__global__ void __launch_bounds__(256)
hash_kernel(const float* __restrict__ qk,
            const float* __restrict__ rot,
            int* __restrict__ bucket) {
    int bh = blockIdx.x >> 3;      // (b*H + h)
    int tc = blockIdx.x & 7;       // 512-token chunk
    int h = bh & 7;
    int b = bh >> 3;

    __shared__ float rl[64 * 32];
    #pragma unroll
    for (int k = 0; k < 8; k++) {
        int e = k * 256 + threadIdx.x;
        rl[e] = rot[(e >> 5) * (H_ * 32) + h * 32 + (e & 31)];
    }
    __syncthreads();

    const int t0 = tc * 512 + threadIdx.x;   // tokens t0, t0+256

    const float4* qrow0 = (const float4*)(qk + ((size_t)(b * S_ + t0)) * D_);
    const float4* qrow1 = (const float4*)(qk + ((size_t)(b * S_ + t0 + 256)) * D_);

    float acc[2][32];
    #pragma unroll
    for (int u = 0; u < 2; u++)
        #pragma unroll
        for (int i = 0; i < 32; i++) acc[u][i] = 0.f;

    for (int k = 0; k < 16; k++) {
        float4 x0 = qrow0[k];
        float4 x1 = qrow1[k];
        const float* r0 = &rl[(4 * k + 0) * 32];
        const float* r1 = &rl[(4 * k + 1) * 32];
        const float* r2 = &rl[(4 * k + 2) * 32];
        const float* r3 = &rl[(4 * k + 3) * 32];
        #pragma unroll
        for (int i = 0; i < 32; i++) {
            float a0 = r0[i], a1 = r1[i], a2 = r2[i], a3 = r3[i];
            acc[0][i] += x0.x * a0 + x0.y * a1 + x0.z * a2 + x0.w * a3;
            acc[1][i] += x1.x * a0 + x1.y * a1 + x1.z * a2 + x1.w * a3;
        }
    }

    #pragma unroll
    for (int u = 0; u < 2; u++) {
        float best = acc[u][0];
        int bi = 0;
        #pragma unroll
        for (int i = 1; i < 32; i++)
            if (acc[u][i] > best) { best = acc[u][i]; bi = i; }
        #pragma unroll
        for (int i = 0; i < 32; i++) {
            float nv = -acc[u][i];
            if (nv > best) { best = nv; bi = 32 + i; }
        }
        bucket[bh * S_ + t0 + 256 * u] = bi;
    }
}

// ---------------- K2: per-(b,h) stable counting sort ----------------
__global__ void sort_kernel(const int* __restrict__ bucket,
                            int* __restrict__ st) {
    int bh = blockIdx.x;
    int lane = threadIdx.x;
    __shared__ int bl[S_];
    __shared__ int cnt[64 * 64];
    __shared__ int tot[64];
    __shared__ int start[64];

    const int base = bh * S_;
    for (int k = 0; k < 64; k++) bl[k * 64 + lane] = bucket[base + k * 64 + lane];
    for (int k = 0; k < 64; k++) cnt[k * 64 + lane] = 0;
    __syncthreads();

    {
        int g = lane;
        for (int j = 0; j < 64; j++) cnt[g * 64 + bl[g * 64 + j]]++;
    }
    __syncthreads();
    {
        int bk = lane, s = 0;
        for (int g = 0; g < 64; g++) s += cnt[g * 64 + bk];
        tot[bk] = s;
    }
    __syncthreads();
    if (lane == 0) {
        int run = 0;
        for (int bk = 0; bk < 64; bk++) { start[bk] = run; run += tot[bk]; }
    }
    __syncthreads();
    {
        int bk = lane;
        int run = start[bk];
        for (int g = 0; g < 64; g++) {
            int c = cnt[g * 64 + bk];
            cnt[g * 64 + bk] = run;
            run += c;
        }
    }
    __syncthreads();
    {
        int g = lane;
        for (int j = 0; j < 64; j++) {
            int t = g * 64 + j;
            int bk = bl[t];
            int p = cnt[g * 64 + bk]++;
            st[base + p] = t;
        }
    }
}

// ---------------- K3: MFMA chunked attention ----------------
// Block = 1 chunk (64 q x 128 kv), 4 waves. No Q staging: Q_i = nrm_i*K_i
// exactly, so dots = nrm_i * (K K^T); rows of the QK^T C-fragment are scaled
// by bounds[i]. V^T (dword-packed token pairs, XOR-q4 swizzled) aliases the
// K region after QK^T. LDS ~36.6 KB -> 4 blocks/CU.
__global__ void __launch_bounds__(256, 4)
attn_kernel(const float* __restrict__ qk,
            const float* __restrict__ v,
            const int* __restrict__ st,
            unsigned short* __restrict__ ou,   // bf16 (B,H,S,D)
            float* __restrict__ lse_u) {       // (B,H,S)
    const int tid = threadIdx.x;
    const int b = blockIdx.x >> 9;
    const int cc = blockIdx.x & 511;
    const int prev = (cc - 1) & 511;
    const int h = cc >> 6;

    __shared__ alignas(16) unsigned short KV[128 * QS_];  // K rows, then V^T
    __shared__ alignas(16) unsigned short Ps[64 * VS_];   // P (then O) per-wave
    __shared__ int tkv[128];
    __shared__ float bounds[64];

    const int stBase = b * (CHUNKS_ * M_);
    if (tid < 128) tkv[tid] = st[stBase + (tid < 64 ? cc : prev) * 64 + (tid & 63)];
    __syncthreads();

    const int stok = tid >> 2;                 // 0..63 (token within pass)
    const int q4 = tid & 3;                    // 16-feature slice

    // ---- stage normalized K; hold V (packed bf16) in regs ----
    unsigned vpk[2][8];
    #pragma unroll
    for (int p = 0; p < 2; p++) {
        int tok = p * 64 + stok;
        int pos = tkv[tok];
        const float4* src = (const float4*)(qk + (size_t)(b * S_ + pos) * 64) + q4 * 4;
        float4 x0 = src[0], x1 = src[1], x2 = src[2], x3 = src[3];
        const float4* vsrc = (const float4*)(v + (size_t)(b * S_ + pos) * 64) + q4 * 4;
        float4 y0 = vsrc[0], y1 = vsrc[1], y2 = vsrc[2], y3 = vsrc[3];

        float ss = x0.x*x0.x + x0.y*x0.y + x0.z*x0.z + x0.w*x0.w
                 + x1.x*x1.x + x1.y*x1.y + x1.z*x1.z + x1.w*x1.w
                 + x2.x*x2.x + x2.y*x2.y + x2.z*x2.z + x2.w*x2.w
                 + x3.x*x3.x + x3.y*x3.y + x3.z*x3.z + x3.w*x3.w;
        ss += __shfl_xor(ss, 1);
        ss += __shfl_xor(ss, 2);
        float nrm = sqrtf(ss);
        float rn = 1.f / fmaxf(nrm, 1e-12f);

        float4 k0 = make_float4(x0.x*rn, x0.y*rn, x0.z*rn, x0.w*rn);
        float4 k1 = make_float4(x1.x*rn, x1.y*rn, x1.z*rn, x1.w*rn);
        float4 k2 = make_float4(x2.x*rn, x2.y*rn, x2.z*rn, x2.w*rn);
        float4 k3 = make_float4(x3.x*rn, x3.y*rn, x3.z*rn, x3.w*rn);
        *(uint4*)&KV[tok * QS_ + q4 * 16]     = pack8(k0, k1);
        *(uint4*)&KV[tok * QS_ + q4 * 16 + 8] = pack8(k2, k3);

        vpk[p][0] = pk2(y0.x, y0.y); vpk[p][1] = pk2(y0.z, y0.w);
        vpk[p][2] = pk2(y1.x, y1.y); vpk[p][3] = pk2(y1.z, y1.w);
        vpk[p][4] = pk2(y2.x, y2.y); vpk[p][5] = pk2(y2.z, y2.w);
        vpk[p][6] = pk2(y3.x, y3.y); vpk[p][7] = pk2(y3.z, y3.w);

        if (p == 0 && q4 == 0) bounds[tok] = nrm * 0.125f;
    }
    __syncthreads();

    const int lane = tid & 63;
    const int w = tid >> 6;
    const int lm = lane & 15;
    const int lq = lane >> 4;

    // ---- K K^T (rows = q-chunk tokens 0..63) ----
    const short8 a0 = *(const short8*)&KV[(w * 16 + lm) * QS_ + lq * 8];
    const short8 a1 = *(const short8*)&KV[(w * 16 + lm) * QS_ + 32 + lq * 8];
    floatx4 C[8];
    #pragma unroll
    for (int nt = 0; nt < 8; nt++) {
        const short8 b0 = *(const short8*)&KV[(nt * 16 + lm) * QS_ + lq * 8];
        const short8 b1 = *(const short8*)&KV[(nt * 16 + lm) * QS_ + 32 + lq * 8];
        floatx4 c = {0.f, 0.f, 0.f, 0.f};
        c = __builtin_amdgcn_mfma_f32_16x16x32_bf16(a0, b0, c, 0, 0, 0);
        c = __builtin_amdgcn_mfma_f32_16x16x32_bf16(a1, b1, c, 0, 0, 0);
        C[nt] = c;
    }

    // ---- mask + exp (bound trick, row-scaled) + P->LDS (A-layout) ----
    int tqr[4]; float bndr[4], bl2[4];
    #pragma unroll
    for (int r = 0; r < 4; r++) {
        int row = w * 16 + lq * 4 + r;
        tqr[r] = tkv[row];
        bndr[r] = bounds[row];
        bl2[r] = bndr[r] * LOG2E;
    }
    float lsum[4] = {0.f, 0.f, 0.f, 0.f};
    #pragma unroll
    for (int nt = 0; nt < 8; nt++) {
        int tkc = tkv[nt * 16 + lm];
        #pragma unroll
        for (int r = 0; r < 4; r++) {
            // d - bound = (C-1) * nrm * 0.125
            float pp = (tkc < tqr[r]) ? exp2f((C[nt][r] - 1.f) * bl2[r]) : 0.f;
            lsum[r] += pp;
            Ps[(w * 16 + lq * 4 + r) * VS_ + nt * 16 + lm] = f2bf(pp);
        }
    }
    #pragma unroll
    for (int r = 0; r < 4; r++) {
        #pragma unroll
        for (int s = 1; s < 16; s <<= 1)
            lsum[r] += __shfl_xor(lsum[r], s);
    }
    __syncthreads();   // all waves done reading K

    // ---- restage V^T over K region: dword = (token 2pd, 2pd+1), b32 writes ----
    {
        unsigned* VT = (unsigned*)KV;
        const int par = stok & 1;
        #pragma unroll
        for (int p = 0; p < 2; p++) {
            int pd = p * 32 + (stok >> 1);
            int pdw = pd ^ (q4 << 3);          // swizzle keyed on writer q4 = f>>4
            #pragma unroll
            for (int i = 0; i < 8; i++) {
                unsigned mine = vpk[p][i];
                unsigned theirs = (unsigned)__shfl_xor((int)mine, 4);
                unsigned out = par ? ((theirs >> 16) | (mine & 0xFFFF0000u))
                                   : ((mine & 0xFFFFu) | (theirs << 16));
                VT[(q4 * 16 + 2 * i + par) * VTS_ + pdw] = out;
            }
        }
    }
    __syncthreads();

    // ---- PV ----
    const unsigned* VT = (const unsigned*)KV;
    floatx4 O[4];
    #pragma unroll
    for (int nt2 = 0; nt2 < 4; nt2++) O[nt2] = floatx4{0.f, 0.f, 0.f, 0.f};
    #pragma unroll
    for (int kt = 0; kt < 4; kt++) {
        const short8 pa = *(const short8*)&Ps[(w * 16 + lm) * VS_ + kt * 32 + lq * 8];
        #pragma unroll
        for (int nt2 = 0; nt2 < 4; nt2++) {
            int base = (nt2 * 16 + lm) * VTS_ + ((kt * 16 + lq * 4) ^ (nt2 << 3));
            const short8 vb = *(const short8*)&VT[base];
            O[nt2] = __builtin_amdgcn_mfma_f32_16x16x32_bf16(pa, vb, O[nt2], 0, 0, 0);
        }
    }

    // ---- epilogue (bf16 out via per-wave LDS transpose) ----
    const size_t oBaseBH = (size_t)(b * H_ + h) * S_;
    #pragma unroll
    for (int r = 0; r < 4; r++) {
        int pos = tqr[r];
        float invl, lse;
        if (lsum[r] > 0.f) {
            invl = 1.f / lsum[r];
            lse = bndr[r] + log2f(lsum[r]) * LN2;
        } else {
            // all candidates masked: out = v[pos] exactly; lse = -50000+log(nself)
            float ns = 0.f;
            #pragma unroll
            for (int nt = 0; nt < 8; nt++)
                ns += (tkv[nt * 16 + lm] == tqr[r]) ? 1.f : 0.f;
            #pragma unroll
            for (int s = 1; s < 16; s <<= 1)
                ns += __shfl_xor(ns, s);
            invl = 1.f;
            lse = -50000.f + logf(ns);
            #pragma unroll
            for (int nt2 = 0; nt2 < 4; nt2++)
                O[nt2][r] = v[(size_t)(b * S_ + pos) * 64 + nt2 * 16 + lm];
        }
        #pragma unroll
        for (int nt2 = 0; nt2 < 4; nt2++)
            Ps[(w * 16 + lq * 4 + r) * VS_ + nt2 * 16 + lm] = f2bf(O[nt2][r] * invl);
        if (lm == 0) lse_u[oBaseBH + pos] = lse;
    }
    {
        int rrow = lane >> 2;
        int seg = lane & 3;
        int qrow = w * 16 + rrow;
        int pos = tkv[qrow];
        uint4 u0 = *(uint4*)&Ps[qrow * VS_ + seg * 16];
        uint4 u1 = *(uint4*)&Ps[qrow * VS_ + seg * 16 + 8];
        unsigned short* dst = ou + (oBaseBH + pos) * 64 + seg * 16;
        *(uint4*)dst = u0;
        *(uint4*)(dst + 8) = u1;
    }
}

// ---------------- K4: combine hash rounds ----------------
__global__ void combine_kernel(const unsigned short* __restrict__ ou,
                               const float* __restrict__ lse_u,
                               float* __restrict__ out) {
    int idx = blockIdx.x * 256 + threadIdx.x;
    int f = idx & 63;
    int t = (idx >> 6) & (S_ - 1);
    int b = idx >> 18;

    const float* lp = lse_u + (size_t)b * (H_ * S_) + t;
    float le[H_];
    float m = -3.4e38f;
    #pragma unroll
    for (int h = 0; h < H_; h++) {
        le[h] = lp[h * S_];
        m = fmaxf(m, le[h]);
    }
    float s = 0.f, e[H_];
    #pragma unroll
    for (int h = 0; h < H_; h++) {
        e[h] = exp2f((le[h] - m) * LOG2E);
        s += e[h];
    }
    float o = 0.f;
    #pragma unroll
    for (int h = 0; h < H_; h++) {
        unsigned short u = ou[(size_t)((b * H_ + h) * S_ + t) * D_ + f];
        o += e[h] * bf2f(u);
    }
    out[idx] = o / s;
}

extern "C" void kernel_launch(void* const* d_in, const int* in_sizes, int n_in,
                              void* d_out, int out_size, void* d_ws, size_t ws_size,
                              hipStream_t stream) {
    const float* qk  = (const float*)d_in[0];
    const float* v   = (const float*)d_in[1];
    const float* rot = (const float*)d_in[2];
    float* out = (float*)d_out;

    char* ws = (char*)d_ws;
    int* bucket  = (int*)(ws);
    int* st      = (int*)(ws + 2097152);
    float* lse_u = (float*)(ws + 4194304);
    unsigned short* ou = (unsigned short*)(ws + 6291456);   // bf16, 67 MB

    hash_kernel<<<dim3(B_ * H_ * (S_ / 512)), dim3(256), 0, stream>>>(qk, rot, bucket);
    sort_kernel<<<dim3(B_ * H_), dim3(64), 0, stream>>>(bucket, st);
    attn_kernel<<<dim3(B_ * CHUNKS_), dim3(256), 0, stream>>>(qk, v, st, ou, lse_u);
    combine_kernel<<<dim3((B_ * S_ * D_) / 256), dim3(256), 0, stream>>>(ou, lse_u, out);
}

// Round 6
// 221.816 us; speedup vs baseline: 1.9467x; 1.0146x over previous
//
#include <hip/hip_runtime.h>
#include <hip/hip_bf16.h>

#define B_ 16
#define S_ 4096
#define D_ 64
#define H_ 8
#define NB_ 64          // n_buckets
#define M_ 64           // bucket_size
#define CHUNKS_ 512     // per batch = H_*NB_
#define LOG2E 1.4426950408889634f
#define LN2 0.6931471805599453f

#define QS_ 72          // K LDS row stride (shorts)
#define VTS_ 68         // V^T row stride (dwords)
#define PS_ 72          // O-transpose staging row stride (shorts)

typedef short short8 __attribute__((ext_vector_type(8)));
typedef short short4v __attribute__((ext_vector_type(4)));
typedef float floatx4 __attribute__((ext_vector_type(4)));

__device__ __forceinline__ unsigned short f2bf(float x) {
    unsigned int u = __float_as_uint(x);
    unsigned int r = (u + 0x7FFFu + ((u >> 16) & 1u)) >> 16;
    return (unsigned short)r;
}
__device__ __forceinline__ float bf2f(unsigned short s) {
    return __uint_as_float(((unsigned int)s) << 16);
}
__device__ __forceinline__ unsigned pk2(float a, float b) {
    __hip_bfloat162 h = __float22bfloat162_rn(make_float2(a, b));
    return *(unsigned*)&h;
}
__device__ __forceinline__ uint4 pack8(float4 a, float4 b) {
    uint4 u;
    u.x = pk2(a.x, a.y); u.y = pk2(a.z, a.w);
    u.z = pk2(b.x, b.y); u.w = pk2(b.z, b.w);
    return u;
}
__device__ __forceinline__ short4v mk4(unsigned lo, unsigned hi) {
    uint2 t = make_uint2(lo, hi);
    return *(short4v*)&t;
}

// ---------------- K1: hashing ----------------
// FROZEN FP ORDER (bucket decisions must not change; absmax is pinned to one
// hash-flip token). 2 tokens/thread, rot broadcast from LDS.
__global__ void __launch_bounds__(256)
hash_kernel(const float* __restrict__ qk,
            const float* __restrict__ rot,
            int* __restrict__ bucket) {
    int bh = blockIdx.x >> 3;      // (b*H + h)
    int tc = blockIdx.x & 7;       // 512-token chunk
    int h = bh & 7;
    int b = bh >> 3;

    __shared__ float rl[64 * 32];
    #pragma unroll
    for (int k = 0; k < 8; k++) {
        int e = k * 256 + threadIdx.x;
        rl[e] = rot[(e >> 5) * (H_ * 32) + h * 32 + (e & 31)];
    }
    __syncthreads();

    const int t0 = tc * 512 + threadIdx.x;   // tokens t0, t0+256

    const float4* qrow0 = (const float4*)(qk + ((size_t)(b * S_ + t0)) * D_);
    const float4* qrow1 = (const float4*)(qk + ((size_t)(b * S_ + t0 + 256)) * D_);

    float acc[2][32];
    #pragma unroll
    for (int u = 0; u < 2; u++)
        #pragma unroll
        for (int i = 0; i < 32; i++) acc[u][i] = 0.f;

    for (int k = 0; k < 16; k++) {
        float4 x0 = qrow0[k];
        float4 x1 = qrow1[k];
        const float* r0 = &rl[(4 * k + 0) * 32];
        const float* r1 = &rl[(4 * k + 1) * 32];
        const float* r2 = &rl[(4 * k + 2) * 32];
        const float* r3 = &rl[(4 * k + 3) * 32];
        #pragma unroll
        for (int i = 0; i < 32; i++) {
            float a0 = r0[i], a1 = r1[i], a2 = r2[i], a3 = r3[i];
            acc[0][i] += x0.x * a0 + x0.y * a1 + x0.z * a2 + x0.w * a3;
            acc[1][i] += x1.x * a0 + x1.y * a1 + x1.z * a2 + x1.w * a3;
        }
    }

    #pragma unroll
    for (int u = 0; u < 2; u++) {
        float best = acc[u][0];
        int bi = 0;
        #pragma unroll
        for (int i = 1; i < 32; i++)
            if (acc[u][i] > best) { best = acc[u][i]; bi = i; }
        #pragma unroll
        for (int i = 0; i < 32; i++) {
            float nv = -acc[u][i];
            if (nv > best) { best = nv; bi = 32 + i; }
        }
        bucket[bh * S_ + t0 + 256 * u] = bi;
    }
}

// ---------------- K2: per-(b,h) stable counting sort ----------------
__global__ void sort_kernel(const int* __restrict__ bucket,
                            int* __restrict__ st) {
    int bh = blockIdx.x;
    int lane = threadIdx.x;
    __shared__ int bl[S_];
    __shared__ int cnt[64 * 64];
    __shared__ int tot[64];
    __shared__ int start[64];

    const int base = bh * S_;
    for (int k = 0; k < 64; k++) bl[k * 64 + lane] = bucket[base + k * 64 + lane];
    for (int k = 0; k < 64; k++) cnt[k * 64 + lane] = 0;
    __syncthreads();

    {
        int g = lane;
        for (int j = 0; j < 64; j++) cnt[g * 64 + bl[g * 64 + j]]++;
    }
    __syncthreads();
    {
        int bk = lane, s = 0;
        for (int g = 0; g < 64; g++) s += cnt[g * 64 + bk];
        tot[bk] = s;
    }
    __syncthreads();
    if (lane == 0) {
        int run = 0;
        for (int bk = 0; bk < 64; bk++) { start[bk] = run; run += tot[bk]; }
    }
    __syncthreads();
    {
        int bk = lane;
        int run = start[bk];
        for (int g = 0; g < 64; g++) {
            int c = cnt[g * 64 + bk];
            cnt[g * 64 + bk] = run;
            run += c;
        }
    }
    __syncthreads();
    {
        int g = lane;
        for (int j = 0; j < 64; j++) {
            int t = g * 64 + j;
            int bk = bl[t];
            int p = cnt[g * 64 + bk]++;
            st[base + p] = t;
        }
    }
}

// ---------------- K3: MFMA chunked attention ----------------
// Block = 1 chunk (64 q x 128 kv), 4 waves. S^T = K_kv * Q^T via x32 MFMA:
// its C-layout (row=kv, col=q) IS the A-layout of 16x16x16 MFMA, so P feeds
// PV straight from registers — no P LDS roundtrip. V^T aliases K region.
// LDS ~28 KB -> 5 blocks/CU.
__global__ void __launch_bounds__(256, 5)
attn_kernel(const float* __restrict__ qk,
            const float* __restrict__ v,
            const int* __restrict__ st,
            unsigned short* __restrict__ ou,   // bf16 (B,H,S,D)
            float* __restrict__ lse_u) {       // (B,H,S)
    const int tid = threadIdx.x;
    const int b = blockIdx.x >> 9;
    const int cc = blockIdx.x & 511;
    const int prev = (cc - 1) & 511;
    const int h = cc >> 6;

    __shared__ alignas(16) unsigned short KV[128 * QS_];  // K rows, then V^T
    __shared__ alignas(16) unsigned short Ps[64 * PS_];   // O transpose staging
    __shared__ int tkv[128];
    __shared__ float bounds[64];

    const int stBase = b * (CHUNKS_ * M_);
    if (tid < 128) tkv[tid] = st[stBase + (tid < 64 ? cc : prev) * 64 + (tid & 63)];
    __syncthreads();

    const int stok = tid >> 2;                 // 0..63 (token within pass)
    const int q4 = tid & 3;                    // 16-feature slice

    // ---- stage normalized K; hold V (packed bf16) in regs ----
    unsigned vpk[2][8];
    #pragma unroll
    for (int p = 0; p < 2; p++) {
        int tok = p * 64 + stok;
        int pos = tkv[tok];
        const float4* src = (const float4*)(qk + (size_t)(b * S_ + pos) * 64) + q4 * 4;
        float4 x0 = src[0], x1 = src[1], x2 = src[2], x3 = src[3];
        const float4* vsrc = (const float4*)(v + (size_t)(b * S_ + pos) * 64) + q4 * 4;
        float4 y0 = vsrc[0], y1 = vsrc[1], y2 = vsrc[2], y3 = vsrc[3];

        float ss = x0.x*x0.x + x0.y*x0.y + x0.z*x0.z + x0.w*x0.w
                 + x1.x*x1.x + x1.y*x1.y + x1.z*x1.z + x1.w*x1.w
                 + x2.x*x2.x + x2.y*x2.y + x2.z*x2.z + x2.w*x2.w
                 + x3.x*x3.x + x3.y*x3.y + x3.z*x3.z + x3.w*x3.w;
        ss += __shfl_xor(ss, 1);
        ss += __shfl_xor(ss, 2);
        float nrm = sqrtf(ss);
        float rn = 1.f / fmaxf(nrm, 1e-12f);

        float4 k0 = make_float4(x0.x*rn, x0.y*rn, x0.z*rn, x0.w*rn);
        float4 k1 = make_float4(x1.x*rn, x1.y*rn, x1.z*rn, x1.w*rn);
        float4 k2 = make_float4(x2.x*rn, x2.y*rn, x2.z*rn, x2.w*rn);
        float4 k3 = make_float4(x3.x*rn, x3.y*rn, x3.z*rn, x3.w*rn);
        *(uint4*)&KV[tok * QS_ + q4 * 16]     = pack8(k0, k1);
        *(uint4*)&KV[tok * QS_ + q4 * 16 + 8] = pack8(k2, k3);

        vpk[p][0] = pk2(y0.x, y0.y); vpk[p][1] = pk2(y0.z, y0.w);
        vpk[p][2] = pk2(y1.x, y1.y); vpk[p][3] = pk2(y1.z, y1.w);
        vpk[p][4] = pk2(y2.x, y2.y); vpk[p][5] = pk2(y2.z, y2.w);
        vpk[p][6] = pk2(y3.x, y3.y); vpk[p][7] = pk2(y3.z, y3.w);

        if (p == 0 && q4 == 0) bounds[tok] = nrm * 0.125f;
    }
    __syncthreads();

    const int lane = tid & 63;
    const int w = tid >> 6;
    const int lm = lane & 15;
    const int lq = lane >> 4;

    // ---- per-lane q scalars (col = lm) ----
    const int   tq  = tkv[w * 16 + lm];
    const float bnd = bounds[w * 16 + lm];
    const float bl2 = bnd * LOG2E;

    // ---- S^T = K * Q^T (A = kv rows, B = q rows of wave w) ----
    const short8 bq0 = *(const short8*)&KV[(w * 16 + lm) * QS_ + lq * 8];
    const short8 bq1 = *(const short8*)&KV[(w * 16 + lm) * QS_ + 32 + lq * 8];
    floatx4 C[8];
    #pragma unroll
    for (int nt = 0; nt < 8; nt++) {
        const short8 a0 = *(const short8*)&KV[(nt * 16 + lm) * QS_ + lq * 8];
        const short8 a1 = *(const short8*)&KV[(nt * 16 + lm) * QS_ + 32 + lq * 8];
        floatx4 c = {0.f, 0.f, 0.f, 0.f};
        c = __builtin_amdgcn_mfma_f32_16x16x32_bf16(a0, bq0, c, 0, 0, 0);
        c = __builtin_amdgcn_mfma_f32_16x16x32_bf16(a1, bq1, c, 0, 0, 0);
        C[nt] = c;
    }

    // ---- mask + exp (bound trick) -> P kept in registers as x16 A-frags ----
    float lsum = 0.f, ns = 0.f;
    short4v pa[8];
    #pragma unroll
    for (int nt = 0; nt < 8; nt++) {
        int4 tki = *(const int4*)&tkv[nt * 16 + lq * 4];   // kv pos, r=0..3
        float p0 = (tki.x < tq) ? exp2f((C[nt][0] - 1.f) * bl2) : 0.f;
        float p1 = (tki.y < tq) ? exp2f((C[nt][1] - 1.f) * bl2) : 0.f;
        float p2 = (tki.z < tq) ? exp2f((C[nt][2] - 1.f) * bl2) : 0.f;
        float p3 = (tki.w < tq) ? exp2f((C[nt][3] - 1.f) * bl2) : 0.f;
        ns += (tki.x == tq) ? 1.f : 0.f;
        ns += (tki.y == tq) ? 1.f : 0.f;
        ns += (tki.z == tq) ? 1.f : 0.f;
        ns += (tki.w == tq) ? 1.f : 0.f;
        lsum += (p0 + p1) + (p2 + p3);
        pa[nt] = mk4(pk2(p0, p1), pk2(p2, p3));
    }
    lsum += __shfl_xor(lsum, 16);
    lsum += __shfl_xor(lsum, 32);
    ns   += __shfl_xor(ns, 16);
    ns   += __shfl_xor(ns, 32);
    __syncthreads();   // all waves done reading K region

    // ---- restage V^T over K region (dword = token pair, XOR-q4 swizzle) ----
    {
        unsigned* VT = (unsigned*)KV;
        const int par = stok & 1;
        #pragma unroll
        for (int p = 0; p < 2; p++) {
            int pd = p * 32 + (stok >> 1);
            int pdw = pd ^ (q4 << 3);
            #pragma unroll
            for (int i = 0; i < 8; i++) {
                unsigned mine = vpk[p][i];
                unsigned theirs = (unsigned)__shfl_xor((int)mine, 4);
                unsigned outw = par ? ((theirs >> 16) | (mine & 0xFFFF0000u))
                                    : ((mine & 0xFFFFu) | (theirs << 16));
                VT[(q4 * 16 + 2 * i + par) * VTS_ + pdw] = outw;
            }
        }
    }
    __syncthreads();

    // ---- PV: O[q][feat] via 16x16x16, A = pa (registers), B = V^T b64 reads ----
    const unsigned* VT = (const unsigned*)KV;
    floatx4 O[4];
    #pragma unroll
    for (int nt2 = 0; nt2 < 4; nt2++) O[nt2] = floatx4{0.f, 0.f, 0.f, 0.f};
    #pragma unroll
    for (int kt = 0; kt < 8; kt++) {
        #pragma unroll
        for (int nt2 = 0; nt2 < 4; nt2++) {
            const short4v vb = *(const short4v*)&VT[(nt2 * 16 + lm) * VTS_
                                + ((kt ^ nt2) * 8 + lq * 2)];
            O[nt2] = __builtin_amdgcn_mfma_f32_16x16x16bf16_1k(pa[kt], vb, O[nt2], 0, 0, 0);
        }
    }

    // ---- epilogue ----
    const size_t oBaseBH = (size_t)(b * H_ + h) * S_;
    #pragma unroll
    for (int r = 0; r < 4; r++) {
        int qrow = w * 16 + lq * 4 + r;
        int pos = tkv[qrow];
        float s = __shfl(lsum, lq * 4 + r);
        float invl;
        if (s > 0.f) {
            invl = 1.f / s;
        } else {
            invl = 1.f;
            #pragma unroll
            for (int nt2 = 0; nt2 < 4; nt2++)
                O[nt2][r] = v[(size_t)(b * S_ + pos) * 64 + nt2 * 16 + lm];
        }
        #pragma unroll
        for (int nt2 = 0; nt2 < 4; nt2++)
            Ps[qrow * PS_ + nt2 * 16 + lm] = f2bf(O[nt2][r] * invl);
    }
    if (lq == 0) {
        float lse = (lsum > 0.f) ? (bnd + log2f(lsum) * LN2)
                                 : (-50000.f + logf(ns));
        lse_u[oBaseBH + tq] = lse;
    }
    {
        int rrow = lane >> 2;
        int seg = lane & 3;
        int qrow = w * 16 + rrow;
        int pos = tkv[qrow];
        uint4 u0 = *(uint4*)&Ps[qrow * PS_ + seg * 16];
        uint4 u1 = *(uint4*)&Ps[qrow * PS_ + seg * 16 + 8];
        unsigned short* dst = ou + (oBaseBH + pos) * 64 + seg * 16;
        *(uint4*)dst = u0;
        *(uint4*)(dst + 8) = u1;
    }
}

// ---------------- K4: combine hash rounds ----------------
__global__ void combine_kernel(const unsigned short* __restrict__ ou,
                               const float* __restrict__ lse_u,
                               float* __restrict__ out) {
    int idx = blockIdx.x * 256 + threadIdx.x;
    int f = idx & 63;
    int t = (idx >> 6) & (S_ - 1);
    int b = idx >> 18;

    const float* lp = lse_u + (size_t)b * (H_ * S_) + t;
    float le[H_];
    float m = -3.4e38f;
    #pragma unroll
    for (int h = 0; h < H_; h++) {
        le[h] = lp[h * S_];
        m = fmaxf(m, le[h]);
    }
    float s = 0.f, e[H_];
    #pragma unroll
    for (int h = 0; h < H_; h++) {
        e[h] = exp2f((le[h] - m) * LOG2E);
        s += e[h];
    }
    float o = 0.f;
    #pragma unroll
    for (int h = 0; h < H_; h++) {
        unsigned short u = ou[(size_t)((b * H_ + h) * S_ + t) * D_ + f];
        o += e[h] * bf2f(u);
    }
    out[idx] = o / s;
}

extern "C" void kernel_launch(void* const* d_in, const int* in_sizes, int n_in,
                              void* d_out, int out_size, void* d_ws, size_t ws_size,
                              hipStream_t stream) {
    const float* qk  = (const float*)d_in[0];
    const float* v   = (const float*)d_in[1];
    const float* rot = (const float*)d_in[2];
    float* out = (float*)d_out;

    char* ws = (char*)d_ws;
    int* bucket  = (int*)(ws);
    int* st      = (int*)(ws + 2097152);
    float* lse_u = (float*)(ws + 4194304);
    unsigned short* ou = (unsigned short*)(ws + 6291456);   // bf16, 67 MB

    hash_kernel<<<dim3(B_ * H_ * (S_ / 512)), dim3(256), 0, stream>>>(qk, rot, bucket);
    sort_kernel<<<dim3(B_ * H_), dim3(64), 0, stream>>>(bucket, st);
    attn_kernel<<<dim3(B_ * CHUNKS_), dim3(256), 0, stream>>>(qk, v, st, ou, lse_u);
    combine_kernel<<<dim3((B_ * S_ * D_) / 256), dim3(256), 0, stream>>>(ou, lse_u, out);
}